// Round 9
// baseline (241.175 us; speedup 1.0000x reference)
//
#include <hip/hip_runtime.h>
#include <math.h>

#define LSEQ 128
#define BB 8
#define M_TOK (BB*LSEQ)   // 1024

typedef __attribute__((ext_vector_type(8))) short short8;
typedef __attribute__((ext_vector_type(4))) float floatx4;

__device__ __forceinline__ unsigned short bf16_rne(float v) {
    union { float f; unsigned u; } a; a.f = v;
    return (unsigned short)((a.u + 0x7fffu + ((a.u >> 16) & 1u)) >> 16);
}
__device__ __forceinline__ float bf16_to_f(unsigned short h) {
    union { unsigned u; float f; } b; b.u = ((unsigned)h) << 16;
    return b.f;
}
__device__ __forceinline__ void split2(float v, unsigned short& h, unsigned short& l) {
    h = bf16_rne(v);
    l = bf16_rne(v - bf16_to_f(h));
}

// ---------------- staging: pack conv weights (split bf16, MFMA B-layout),
// embedding gather+split, Wfc — one launch ----------------
struct PreArgs {
    const float *w1, *w2, *w3, *w4, *w5;
    unsigned short *B1h, *B1l, *B2h, *B2l, *B3h, *B3l, *B4h, *B4l, *B5h, *B5l;
    const int* x;
    const float* gen;
    const float* dom;
    unsigned short *Eh, *El;
    const float* wf;
    const float* wc;
    float* Wfc;
};
__global__ __launch_bounds__(256) void stage_kernel(PreArgs a) {
    int y = blockIdx.y;
    int tid = threadIdx.x;
    if (y < 3) {
        const float* w = (y == 0) ? a.w3 : (y == 1) ? a.w4 : a.w5;
        unsigned short* dh = (y == 0) ? a.B3h : (y == 1) ? a.B4h : a.B5h;
        unsigned short* dl = (y == 0) ? a.B3l : (y == 1) ? a.B4l : a.B5l;
        int idx = blockIdx.x * 256 + tid;          // < 327680 exactly
        int j = idx & 7;
        int n = (idx >> 3) & 255;
        int g = idx >> 11;
        int cg = g & 31, kk = g >> 5;
        int ci = cg * 8 + j;
        float v = w[(n * 256 + ci) * 5 + kk];
        unsigned short h, l; split2(v, h, l);
        dh[idx] = h; dl[idx] = l;
    } else if (y == 3) {
        int idx = blockIdx.x * 256 + tid;
        if (idx >= 5 * 52 * 128 * 8) return;
        int j = idx & 7;
        int n = (idx >> 3) & 127;
        int g = idx >> 10;
        int cg = g % 52, kk = g / 52;
        int ci = cg * 8 + j;
        float v = (ci < 400) ? a.w1[(n * 400 + ci) * 5 + kk] : 0.f;
        unsigned short h, l; split2(v, h, l);
        a.B1h[idx] = h; a.B1l[idx] = l;
    } else if (y == 4) {
        int idx = blockIdx.x * 256 + tid;
        if (idx >= 3 * 52 * 128 * 8) return;
        int j = idx & 7;
        int n = (idx >> 3) & 127;
        int g = idx >> 10;
        int cg = g % 52, kk = g / 52;
        int ci = cg * 8 + j;
        float v = (ci < 400) ? a.w2[(n * 400 + ci) * 3 + kk] : 0.f;
        unsigned short h, l; split2(v, h, l);
        a.B2h[idx] = h; a.B2l[idx] = l;
    } else if (y == 5) {
        int m = blockIdx.x;
        if (m >= M_TOK) return;
        int t = a.x[m];
        for (int c = tid; c < 416; c += 256) {
            float v = (c < 300) ? a.gen[t * 300 + c]
                    : (c < 400) ? a.dom[t * 100 + (c - 300)] : 0.f;
            unsigned short h, l; split2(v, h, l);
            a.Eh[m * 416 + c] = h;
            a.El[m * 416 + c] = l;
        }
    } else {
        // Wfc[r,c] = sum_n wf[r,n]*wc[n,c], r < 512
        int r = blockIdx.x;
        if (r >= 512 || tid >= 64) return;
        int l = tid;
        float p[6] = {0,0,0,0,0,0};
        const float* row = a.wf + r * 512;
        #pragma unroll
        for (int k = 0; k < 8; ++k) {
            int n = l + 64 * k;
            float v = row[n];
            #pragma unroll
            for (int c = 0; c < 6; ++c) p[c] += v * a.wc[n * 6 + c];
        }
        #pragma unroll
        for (int c = 0; c < 6; ++c)
            for (int off = 32; off >= 1; off >>= 1) p[c] += __shfl_xor(p[c], off, 64);
        if (l == 0) {
            #pragma unroll
            for (int c = 0; c < 6; ++c) a.Wfc[r * 6 + c] = p[c];
        }
    }
}

// ---------------- conv1 MFMA (+precomp2 on by==4) ----------------
__global__ __launch_bounds__(256) void conv1_mfma(
        const unsigned short* __restrict__ Eh, const unsigned short* __restrict__ El,
        const unsigned short* __restrict__ B1h, const unsigned short* __restrict__ B1l,
        const unsigned short* __restrict__ B2h, const unsigned short* __restrict__ B2l,
        const float* __restrict__ b1, const float* __restrict__ b2,
        unsigned short* __restrict__ Xoh, unsigned short* __restrict__ Xol,
        const float* __restrict__ wf, const float* __restrict__ bf,
        const float* __restrict__ wc, const float* __restrict__ Wfc,
        float* __restrict__ U) {
    __shared__ __align__(16) unsigned short xsh[20 * 424];
    __shared__ __align__(16) unsigned short xsl[20 * 424];
    int by = blockIdx.y;
    int tid = threadIdx.x;
    if (by == 4) {
        if (tid >= 64) return;
        int l = tid;
        for (int i = 0; i < 9; ++i) {
            int r = blockIdx.x + 64 * i;
            if (r >= 531) break;
            const float* row = (r < 530) ? (wf + r * 512) : bf;
            float p[12];
            #pragma unroll
            for (int c = 0; c < 12; ++c) p[c] = 0.f;
            #pragma unroll
            for (int k = 0; k < 8; ++k) {
                int n = l + 64 * k;
                float v = row[n];
                #pragma unroll
                for (int c = 0; c < 6; ++c) {
                    p[c]     += v * wc[n * 6 + c];
                    p[c + 6] += v * Wfc[n * 6 + c];
                }
            }
            #pragma unroll
            for (int c = 0; c < 12; ++c)
                for (int off = 32; off >= 1; off >>= 1) p[c] += __shfl_xor(p[c], off, 64);
            if (l == 0) {
                #pragma unroll
                for (int c = 0; c < 12; ++c) U[r * 12 + c] = p[c];
            }
        }
        return;
    }
    int mt = blockIdx.x;
    int p0 = mt * 16;
    int b = p0 >> 7, l0 = p0 & 127;
    for (int i = tid; i < 2 * 1040; i += 256) {
        int sel = i >= 1040;
        int u2 = sel ? i - 1040 : i;
        int j = u2 / 52, cg = u2 % 52;
        int l = l0 - 2 + j;
        short8 v = {0,0,0,0,0,0,0,0};
        if (l >= 0 && l < 128) {
            const unsigned short* src = (sel ? El : Eh) + (b * 128 + l) * 416 + cg * 8;
            v = *(const short8*)src;
        }
        *(short8*)((sel ? xsl : xsh) + j * 424 + cg * 8) = v;
    }
    __syncthreads();
    int w = tid >> 6, lane = tid & 63;
    int m = lane & 15, q = lane >> 4;
    bool br2 = (by >= 2);
    int n0b = (by & 1) * 64;
    int nB = n0b + w * 16 + m;
    floatx4 acc0 = {0,0,0,0}, acc1 = {0,0,0,0}, acc2 = {0,0,0,0};
    if (!br2) {
        for (int kk = 0; kk < 5; ++kk) {
            const unsigned short* arh = xsh + (m + kk) * 424;
            const unsigned short* arl = xsl + (m + kk) * 424;
            #pragma unroll
            for (int u = 0; u < 13; ++u) {
                short8 ah = *(const short8*)(arh + u * 32 + q * 8);
                short8 al = *(const short8*)(arl + u * 32 + q * 8);
                int boff = (((kk * 52 + u * 4 + q) * 128) + nB) * 8;
                short8 bh = *(const short8*)(B1h + boff);
                short8 bl = *(const short8*)(B1l + boff);
                acc0 = __builtin_amdgcn_mfma_f32_16x16x32_bf16(ah, bh, acc0, 0, 0, 0);
                acc1 = __builtin_amdgcn_mfma_f32_16x16x32_bf16(ah, bl, acc1, 0, 0, 0);
                acc2 = __builtin_amdgcn_mfma_f32_16x16x32_bf16(al, bh, acc2, 0, 0, 0);
            }
        }
    } else {
        for (int kk = 0; kk < 3; ++kk) {
            const unsigned short* arh = xsh + (m + kk + 1) * 424;
            const unsigned short* arl = xsl + (m + kk + 1) * 424;
            #pragma unroll
            for (int u = 0; u < 13; ++u) {
                short8 ah = *(const short8*)(arh + u * 32 + q * 8);
                short8 al = *(const short8*)(arl + u * 32 + q * 8);
                int boff = (((kk * 52 + u * 4 + q) * 128) + nB) * 8;
                short8 bh = *(const short8*)(B2h + boff);
                short8 bl = *(const short8*)(B2l + boff);
                acc0 = __builtin_amdgcn_mfma_f32_16x16x32_bf16(ah, bh, acc0, 0, 0, 0);
                acc1 = __builtin_amdgcn_mfma_f32_16x16x32_bf16(ah, bl, acc1, 0, 0, 0);
                acc2 = __builtin_amdgcn_mfma_f32_16x16x32_bf16(al, bh, acc2, 0, 0, 0);
            }
        }
    }
    __syncthreads();
    float* fl = (float*)xsh;   // 16 x 68 tile
    #pragma unroll
    for (int reg = 0; reg < 4; ++reg)
        fl[(q * 4 + reg) * 68 + w * 16 + m] = acc0[reg] + acc1[reg] + acc2[reg];
    __syncthreads();
    int ocb = br2 ? 128 + n0b : n0b;
    const float* bias = br2 ? b2 : b1;
    #pragma unroll
    for (int i = 0; i < 4; ++i) {
        int e = tid + 256 * i;
        int mm = e >> 6, nn = e & 63;
        float val = fl[mm * 68 + nn] + bias[n0b + nn];
        val = fmaxf(val, 0.f);
        unsigned short h, l; split2(val, h, l);
        int o = (p0 + mm) * 256 + ocb + nn;
        Xoh[o] = h; Xol[o] = l;
    }
}

// ---------------- conv256 MFMA: 256->256, k=5, p=2, relu; outmode 0=split bf16, 1=fp32 ----------------
__global__ __launch_bounds__(256) void conv256_mfma(
        const unsigned short* __restrict__ Xih, const unsigned short* __restrict__ Xil,
        const unsigned short* __restrict__ Bh, const unsigned short* __restrict__ Bl,
        const float* __restrict__ bias, int outmode,
        unsigned short* __restrict__ Xoh, unsigned short* __restrict__ Xol,
        float* __restrict__ fout) {
    __shared__ __align__(16) unsigned short xsh[20 * 264];
    __shared__ __align__(16) unsigned short xsl[20 * 264];
    int mt = blockIdx.x;
    int p0 = mt * 16;
    int b = p0 >> 7, l0 = p0 & 127;
    int n0 = blockIdx.y * 64;
    int tid = threadIdx.x;
    for (int i = tid; i < 2 * 640; i += 256) {
        int sel = i >= 640;
        int u2 = sel ? i - 640 : i;
        int j = u2 >> 5, cg = u2 & 31;
        int l = l0 - 2 + j;
        short8 v = {0,0,0,0,0,0,0,0};
        if (l >= 0 && l < 128) {
            const unsigned short* src = (sel ? Xil : Xih) + (b * 128 + l) * 256 + cg * 8;
            v = *(const short8*)src;
        }
        *(short8*)((sel ? xsl : xsh) + j * 264 + cg * 8) = v;
    }
    __syncthreads();
    int w = tid >> 6, lane = tid & 63;
    int m = lane & 15, q = lane >> 4;
    int nB = n0 + w * 16 + m;
    floatx4 acc0 = {0,0,0,0}, acc1 = {0,0,0,0}, acc2 = {0,0,0,0};
    for (int kk = 0; kk < 5; ++kk) {
        const unsigned short* arh = xsh + (m + kk) * 264;
        const unsigned short* arl = xsl + (m + kk) * 264;
        #pragma unroll
        for (int u = 0; u < 8; ++u) {
            short8 ah = *(const short8*)(arh + u * 32 + q * 8);
            short8 al = *(const short8*)(arl + u * 32 + q * 8);
            int boff = (((kk * 32 + u * 4 + q) * 256) + nB) * 8;
            short8 bh = *(const short8*)(Bh + boff);
            short8 bl = *(const short8*)(Bl + boff);
            acc0 = __builtin_amdgcn_mfma_f32_16x16x32_bf16(ah, bh, acc0, 0, 0, 0);
            acc1 = __builtin_amdgcn_mfma_f32_16x16x32_bf16(ah, bl, acc1, 0, 0, 0);
            acc2 = __builtin_amdgcn_mfma_f32_16x16x32_bf16(al, bh, acc2, 0, 0, 0);
        }
    }
    __syncthreads();
    float* fl = (float*)xsh;
    #pragma unroll
    for (int reg = 0; reg < 4; ++reg)
        fl[(q * 4 + reg) * 68 + w * 16 + m] = acc0[reg] + acc1[reg] + acc2[reg];
    __syncthreads();
    #pragma unroll
    for (int i = 0; i < 4; ++i) {
        int e = tid + 256 * i;
        int mm = e >> 6, nn = e & 63;
        float val = fl[mm * 68 + nn] + bias[n0 + nn];
        val = fmaxf(val, 0.f);
        int o = (p0 + mm) * 256 + n0 + nn;
        if (outmode == 0) {
            unsigned short h, l; split2(val, h, l);
            Xoh[o] = h; Xol[o] = l;
        } else {
            fout[o] = val;
        }
    }
}

// ---------------- q/v projection ----------------
__global__ __launch_bounds__(128) void qv_v2(const float* __restrict__ xc,
        const float* __restrict__ wq, const float* __restrict__ bq,
        const float* __restrict__ wv, const float* __restrict__ bv,
        float* __restrict__ q, float* __restrict__ v) {
    int m = blockIdx.x;
    int tid = threadIdx.x;
    int w = tid >> 6, d = tid & 63;
    if (d >= 50) return;
    const float* W = w ? wv : wq;
    float a = w ? bv[d] : bq[d];
    const float* xm = xc + m * 256;
    #pragma unroll 8
    for (int c = 0; c < 256; ++c) a += xm[c] * W[c * 50 + d];
    (w ? v : q)[m * 50 + d] = a;
}

// ---------------- attention v2 (+fused f0/g0) ----------------
__global__ __launch_bounds__(256) void attn_v2(const float* __restrict__ xc,
        const float* __restrict__ q, const float* __restrict__ v,
        const float* __restrict__ vv, const float* __restrict__ xmask,
        const float* __restrict__ wc, const float* __restrict__ bc,
        float* __restrict__ xc2, float* __restrict__ f0, float* __restrict__ g0) {
    __shared__ float vs[128 * 50];
    __shared__ float spart[128], aarr[128], xrow[256], qrow[52], vvs[52], red[4];
    int bi = blockIdx.x;
    int b = bi >> 7;
    int tid = threadIdx.x;
    for (int idx = tid; idx < 128 * 50; idx += 256) vs[idx] = v[b * 6400 + idx];
    if (tid < 50) { qrow[tid] = q[bi * 50 + tid]; vvs[tid] = vv[tid]; }
    __syncthreads();
    int j = tid & 127, half = tid >> 7;
    int d0 = half * 25;
    const float* vj = vs + j * 50 + d0;
    float s = 0.f;
    #pragma unroll
    for (int d = 0; d < 25; ++d) {
        float x = qrow[d0 + d] + vj[d];
        float e = __expf(2.f * x);               // tanh(x) = 1 - 2/(e^(2x)+1)
        s += (1.f - 2.f / (e + 1.f)) * vvs[d0 + d];
    }
    if (half) spart[j] = s;
    __syncthreads();
    float stot = 0.f;
    if (!half) {
        stot = s + spart[j];
        if (xmask[b * LSEQ + j] == 0.f) stot = -1e9f;
    }
    if (tid < 128) {
        float m = stot;
        #pragma unroll
        for (int off = 32; off >= 1; off >>= 1) m = fmaxf(m, __shfl_xor(m, off, 64));
        if ((tid & 63) == 0) red[tid >> 6] = m;
    }
    __syncthreads();
    float mx = fmaxf(red[0], red[1]);
    float e = 0.f;
    if (tid < 128) {
        e = __expf(stot - mx);
        float su = e;
        #pragma unroll
        for (int off = 32; off >= 1; off >>= 1) su += __shfl_xor(su, off, 64);
        if ((tid & 63) == 0) red[2 + (tid >> 6)] = su;
    }
    __syncthreads();
    float denom = red[2] + red[3];
    if (tid < 128) aarr[j] = e / denom;
    __syncthreads();
    float maskI = xmask[bi];
    const float* xcb = xc + b * LSEQ * 256;
    float acc = 0.f;
    #pragma unroll 8
    for (int jj = 0; jj < 128; ++jj) acc += aarr[jj] * xcb[jj * 256 + tid];
    float val = xc[bi * 256 + tid] + acc * maskI;
    xc2[bi * 256 + tid] = val;
    xrow[tid] = val;
    __syncthreads();
    int grp = tid >> 4, l16 = tid & 15;
    if (grp < 12) {
        int c = grp % 6, gsel = grp / 6;
        const float* wcc = wc + gsel * 256 * 6 + c;
        float a = 0.f;
        #pragma unroll
        for (int ch = l16; ch < 256; ch += 16) a += xrow[ch] * wcc[ch * 6];
        #pragma unroll
        for (int off = 8; off >= 1; off >>= 1) a += __shfl_down(a, off, 16);
        if (l16 == 0) {
            if (gsel == 0) f0[bi * 6 + c] = a + bc[c];
            else           g0[bi * 6 + c] = a;
        }
    }
}

// ---------------- hopfold v2: inline lm0 (max-reduction) + fold ----------------
__global__ __launch_bounds__(64) void hopfold_v2(const float* __restrict__ xc2,
        const float* __restrict__ U, const float* __restrict__ f0,
        const float* __restrict__ g0, const float* __restrict__ bc,
        float* __restrict__ outF, float* __restrict__ outG) {
    int m = blockIdx.x;
    int y = blockIdx.y;
    int tid = threadIdx.x;
    int b = m >> 7, t = m & 127;
    // ---- inline lm0[t,:]: prefix-max f over p<=t, suffix-max g over p>=t ----
    const float* fbp = f0 + b * 768;
    const float* gbp = g0 + b * 768;
    float pf[6], sgm[6];
    #pragma unroll
    for (int c = 0; c < 6; ++c) { pf[c] = -INFINITY; sgm[c] = -INFINITY; }
    #pragma unroll
    for (int r = 0; r < 2; ++r) {
        int p = tid + 64 * r;
        bool fok = (p <= t), gok = (p >= t);
        #pragma unroll
        for (int c = 0; c < 6; ++c) {
            float fv = fbp[p * 6 + c];
            float gv = gbp[p * 6 + c];
            pf[c]  = fmaxf(pf[c],  fok ? fv : -INFINITY);
            sgm[c] = fmaxf(sgm[c], gok ? gv : -INFINITY);
        }
    }
    #pragma unroll
    for (int c = 0; c < 6; ++c) {
        #pragma unroll
        for (int off = 32; off >= 1; off >>= 1) {
            pf[c]  = fmaxf(pf[c],  __shfl_xor(pf[c],  off, 64));
            sgm[c] = fmaxf(sgm[c], __shfl_xor(sgm[c], off, 64));
        }
    }
    // ---- main fold GEMM ----
    const float* Urows = U + (y ? 256 : 0) * 12;
    float acc[12];
    #pragma unroll
    for (int c = 0; c < 12; ++c) acc[c] = 0.f;
    for (int k = tid; k < 256; k += 64) {
        float a = xc2[m * 256 + k];
        const float* ur = Urows + k * 12;
        #pragma unroll
        for (int c = 0; c < 12; ++c) acc[c] += a * ur[c];
    }
    #pragma unroll
    for (int c = 0; c < 12; ++c)
        for (int off = 32; off >= 1; off >>= 1) acc[c] += __shfl_xor(acc[c], off, 64);
    if (tid == 0) {
        const float* Bb = U + (y ? 518 : 512) * 12;
        const float* Db = U + 524 * 12;
        float* out = y ? outG : outF;
        float lmv[6], fgv[6];
        #pragma unroll
        for (int c = 0; c < 6; ++c) {
            float fvt = fbp[t * 6 + c], gvt = gbp[t * 6 + c];
            float M1 = pf[c] + gvt;  if (t < LSEQ - 1) M1 = fmaxf(M1, 0.f);
            float M2 = fvt + sgm[c]; if (t > 0)        M2 = fmaxf(M2, 0.f);
            lmv[c] = fmaxf(M1, M2);
            fgv[c] = y ? gvt : fvt;
        }
        #pragma unroll
        for (int c = 0; c < 12; ++c) {
            float s = acc[c];
            #pragma unroll
            for (int j = 0; j < 6; ++j) s += lmv[j] * Bb[j * 12 + c] + fgv[j] * Db[j * 12 + c];
            if (!y) { s += U[530 * 12 + c]; if (c < 6) s += bc[c]; }
            out[m * 12 + c] = s;
        }
    }
}

// ---------------- tail2: lm1 scan + f2/g2 + writeout, one block per (b,i) ----------------
__global__ __launch_bounds__(128) void tail2_kernel(const float* __restrict__ f1phi,
        const float* __restrict__ g1gam, const float* __restrict__ U,
        const float* __restrict__ bc, float* __restrict__ out) {
    __shared__ float fT[12 * 132], gT[12 * 132];   // [c*132+p]
    __shared__ float pmax[6 * 132], smax[6 * 132];
    __shared__ float Ut[19 * 12], bcs[8];
    int bi = blockIdx.x;          // b*128 + i
    int b = bi >> 7, i = bi & 127;
    int tid = threadIdx.x;
    for (int k = tid; k < 1536; k += 128) {
        int p = k / 12, c = k - p * 12;
        fT[c * 132 + p] = f1phi[b * 1536 + k];
        gT[c * 132 + p] = g1gam[b * 1536 + k];
    }
    for (int k = tid; k < 228; k += 128) Ut[k] = U[512 * 12 + k];
    if (tid < 6) bcs[tid] = bc[tid];
    __syncthreads();
    int w = tid >> 6, l = tid & 63;
    if (w == 0) {
        // prefix-max of f1 (channels 0..5), 2 elems/lane, shfl_up scan
        for (int c = 0; c < 6; ++c) {
            float v0 = fT[c * 132 + 2 * l], v1 = fT[c * 132 + 2 * l + 1];
            float sc = fmaxf(v0, v1);
            #pragma unroll
            for (int off = 1; off < 64; off <<= 1) {
                float o = __shfl_up(sc, off, 64);
                if (l >= off) sc = fmaxf(sc, o);
            }
            float E = __shfl_up(sc, 1, 64); if (l == 0) E = -INFINITY;
            pmax[c * 132 + 2 * l] = fmaxf(E, v0);
            pmax[c * 132 + 2 * l + 1] = sc;
        }
    } else {
        // suffix-max of g1
        for (int c = 0; c < 6; ++c) {
            int i0 = 127 - 2 * l, i1 = 126 - 2 * l;
            float v0 = gT[c * 132 + i0], v1 = gT[c * 132 + i1];
            float sc = fmaxf(v0, v1);
            #pragma unroll
            for (int off = 1; off < 64; off <<= 1) {
                float o = __shfl_up(sc, off, 64);
                if (l >= off) sc = fmaxf(sc, o);
            }
            float E = __shfl_up(sc, 1, 64); if (l == 0) E = -INFINITY;
            smax[c * 132 + i0] = fmaxf(E, v0);
            smax[c * 132 + i1] = sc;
        }
    }
    __syncthreads();
    int j = tid;   // token for g2 row
    // lm1 for token j and token i
    float lmj[6], lmi[6];
    #pragma unroll
    for (int c = 0; c < 6; ++c) {
        float M1 = pmax[c * 132 + j] + gT[c * 132 + j];
        if (j < LSEQ - 1) M1 = fmaxf(M1, 0.f);
        float M2 = fT[c * 132 + j] + smax[c * 132 + j];
        if (j > 0) M2 = fmaxf(M2, 0.f);
        lmj[c] = fmaxf(M1, M2);
        float N1 = pmax[c * 132 + i] + gT[c * 132 + i];
        if (i < LSEQ - 1) N1 = fmaxf(N1, 0.f);
        float N2 = fT[c * 132 + i] + smax[c * 132 + i];
        if (i > 0) N2 = fmaxf(N2, 0.f);
        lmi[c] = fmaxf(N1, N2);
    }
    // f2 row (token i, computed redundantly per thread) and g2 row (token j)
    float res[6];
    #pragma unroll
    for (int c = 0; c < 6; ++c) {
        float sf = fT[(6 + c) * 132 + i] + Ut[18 * 12 + c] + bcs[c];
        float sg = gT[(6 + c) * 132 + j];
        #pragma unroll
        for (int jj = 0; jj < 6; ++jj) {
            sf += lmi[jj] * Ut[jj * 12 + c]       + fT[jj * 132 + i] * Ut[(12 + jj) * 12 + c];
            sg += lmj[jj] * Ut[(6 + jj) * 12 + c] + gT[jj * 132 + j] * Ut[(12 + jj) * 12 + c];
        }
        res[c] = sf + sg;
    }
    float* op = out + (size_t)bi * 768 + j * 6;
    #pragma unroll
    for (int c = 0; c < 6; ++c) op[c] = res[c];
}

extern "C" void kernel_launch(void* const* d_in, const int* in_sizes, int n_in,
                              void* d_out, int out_size, void* d_ws, size_t ws_size,
                              hipStream_t stream) {
    const int*   x     = (const int*)d_in[0];
    const float* xmask = (const float*)d_in[2];
    const float* gen   = (const float*)d_in[3];
    const float* dom   = (const float*)d_in[4];
    const float* w1    = (const float*)d_in[5];
    const float* b1    = (const float*)d_in[6];
    const float* w2    = (const float*)d_in[7];
    const float* b2    = (const float*)d_in[8];
    const float* w3    = (const float*)d_in[9];
    const float* b3    = (const float*)d_in[10];
    const float* w4    = (const float*)d_in[11];
    const float* b4    = (const float*)d_in[12];
    const float* w5    = (const float*)d_in[13];
    const float* b5    = (const float*)d_in[14];
    const float* wq    = (const float*)d_in[15];
    const float* bq    = (const float*)d_in[16];
    const float* wv    = (const float*)d_in[17];
    const float* bv    = (const float*)d_in[18];
    const float* vv    = (const float*)d_in[19];
    const float* wf    = (const float*)d_in[20];
    const float* bf    = (const float*)d_in[21];
    const float* wc    = (const float*)d_in[22];
    const float* bc    = (const float*)d_in[23];

    // fp32 region
    float* fb = (float*)d_ws;
    float* bufB  = fb;                   // 262144  (xc, conv5 out)
    float* xc2   = bufB  + 262144;       // 262144
    float* qb    = xc2   + 262144;       // 51200
    float* vb    = qb    + 51200;        // 51200
    float* Wfc   = vb    + 51200;        // 3072
    float* U     = Wfc   + 3072;         // 6376 (pad)
    float* f0    = U     + 6376;         // 6144
    float* g0    = f0    + 6144;
    float* f1phi = g0    + 6144;         // 12288
    float* g1gam = f1phi + 12288;        // 12288
    // bf16 (ushort) region, 16B aligned
    unsigned short* sb = (unsigned short*)(g1gam + 12288 + 32);
    unsigned short* Eh  = sb;             sb += 425984;  // 1024*416
    unsigned short* El  = sb;             sb += 425984;
    unsigned short* B1h = sb;             sb += 266240;  // 5*52*128*8
    unsigned short* B1l = sb;             sb += 266240;
    unsigned short* B2h = sb;             sb += 159744;  // 3*52*128*8
    unsigned short* B2l = sb;             sb += 159744;
    unsigned short* B3h = sb;             sb += 327680;  // 5*32*256*8
    unsigned short* B3l = sb;             sb += 327680;
    unsigned short* B4h = sb;             sb += 327680;
    unsigned short* B4l = sb;             sb += 327680;
    unsigned short* B5h = sb;             sb += 327680;
    unsigned short* B5l = sb;             sb += 327680;
    unsigned short* X3h = sb;             sb += 262144;  // 1024*256
    unsigned short* X3l = sb;             sb += 262144;
    unsigned short* X4h = sb;             sb += 262144;
    unsigned short* X4l = sb;             sb += 262144;

    // --- staging ---
    PreArgs pa;
    pa.w1 = w1; pa.w2 = w2; pa.w3 = w3; pa.w4 = w4; pa.w5 = w5;
    pa.B1h = B1h; pa.B1l = B1l; pa.B2h = B2h; pa.B2l = B2l;
    pa.B3h = B3h; pa.B3l = B3l; pa.B4h = B4h; pa.B4l = B4l;
    pa.B5h = B5h; pa.B5l = B5l;
    pa.x = x; pa.gen = gen; pa.dom = dom; pa.Eh = Eh; pa.El = El;
    pa.wf = wf; pa.wc = wc; pa.Wfc = Wfc;
    stage_kernel<<<dim3(1280, 7), 256, 0, stream>>>(pa);

    // --- convs (MFMA split-bf16) ---
    conv1_mfma<<<dim3(64, 5), 256, 0, stream>>>(Eh, El, B1h, B1l, B2h, B2l, b1, b2,
                                                X3h, X3l, wf, bf, wc, Wfc, U);
    conv256_mfma<<<dim3(64, 4), 256, 0, stream>>>(X3h, X3l, B3h, B3l, b3, 0,
                                                  X4h, X4l, nullptr);
    conv256_mfma<<<dim3(64, 4), 256, 0, stream>>>(X4h, X4l, B4h, B4l, b4, 0,
                                                  X3h, X3l, nullptr);
    conv256_mfma<<<dim3(64, 4), 256, 0, stream>>>(X3h, X3l, B5h, B5l, b5, 1,
                                                  nullptr, nullptr, bufB);
    // xc = bufB (fp32)

    // --- attention (+ fused f0/g0) ---
    qv_v2<<<M_TOK, 128, 0, stream>>>(bufB, wq, bq, wv, bv, qb, vb);
    attn_v2<<<M_TOK, 256, 0, stream>>>(bufB, qb, vb, vv, xmask, wc, bc, xc2, f0, g0);

    // --- hop tail: 2 launches ---
    hopfold_v2<<<dim3(M_TOK, 2), 64, 0, stream>>>(xc2, U, f0, g0, bc, f1phi, g1gam);
    tail2_kernel<<<M_TOK, 128, 0, stream>>>(f1phi, g1gam, U, bc, (float*)d_out);
}